// Round 3
// baseline (699.182 us; speedup 1.0000x reference)
//
#include <hip/hip_runtime.h>

typedef unsigned short u16;
typedef unsigned int u32;
typedef __bf16 bf16x8 __attribute__((ext_vector_type(8)));
typedef float f32x4 __attribute__((ext_vector_type(4)));

__device__ __forceinline__ u16 f2bf(float f) {
  u32 u = __builtin_bit_cast(u32, f);
  return (u16)((u + 0x7fffu + ((u >> 16) & 1u)) >> 16);  // RNE
}

__device__ __forceinline__ f32x4 mfma16(bf16x8 a, bf16x8 b, f32x4 c) {
  return __builtin_amdgcn_mfma_f32_16x16x32_bf16(a, b, c, 0, 0, 0);
}

struct alignas(8) U16x4 { u16 x, y, z, w; };

#define AS1 __attribute__((address_space(1)))
#define AS3 __attribute__((address_space(3)))
// async global->LDS, 16B per lane; lds dest = wave-uniform base + lane*16
__device__ __forceinline__ void gl16(const u16* g, u16* l) {
  __builtin_amdgcn_global_load_lds((const AS1 u32*)g, (AS3 u32*)l, 16, 0, 0);
}

// ---------------- fp32 -> bf16 convert (vectorized) ----------------
__global__ __launch_bounds__(256) void k_f32_to_bf16(const float* __restrict__ in,
                                                     u16* __restrict__ out, long n4) {
  long i = (long)blockIdx.x * blockDim.x + threadIdx.x;
  long stride = (long)gridDim.x * blockDim.x;
  for (; i < n4; i += stride) {
    float4 v = ((const float4*)in)[i];
    U16x4 o{f2bf(v.x), f2bf(v.y), f2bf(v.z), f2bf(v.w)};
    ((U16x4*)out)[i] = o;
  }
}

// ------------- transpose fp32 [rows][cols] -> bf16 [cols][rows] -------------
__global__ __launch_bounds__(256) void k_transpose_f32_to_bf16(const float* __restrict__ in,
                                                               u16* __restrict__ out,
                                                               int rows, int cols) {
  __shared__ float tile[32][33];
  int bc = blockIdx.x * 32, br = blockIdx.y * 32;
  int tx = threadIdx.x, ty = threadIdx.y;  // 32 x 8
  for (int i = 0; i < 32; i += 8)
    tile[ty + i][tx] = in[(long)(br + ty + i) * cols + bc + tx];
  __syncthreads();
  for (int i = 0; i < 32; i += 8)
    out[(long)(bc + ty + i) * rows + br + tx] = f2bf(tile[tx][ty + i]);
}

// ------------- V slice transpose: QKV[b*T+t][4096+h*128+d] -> Vt[bh][d][t] -------------
__global__ __launch_bounds__(256) void k_transpose_v(const u16* __restrict__ qkv,
                                                     u16* __restrict__ vt) {
  __shared__ u16 tile[32][33];
  int bh = blockIdx.z; int b = bh >> 4, h = bh & 15;
  int t0 = blockIdx.y * 32, d0 = blockIdx.x * 32;
  int tx = threadIdx.x, ty = threadIdx.y;  // 32 x 8
  const u16* src = qkv + (long)(b * 2048) * 6144 + 4096 + h * 128;
  for (int i = 0; i < 32; i += 8)
    tile[ty + i][tx] = src[(long)(t0 + ty + i) * 6144 + d0 + tx];
  __syncthreads();
  u16* dst = vt + (long)bh * 128 * 2048;
  for (int i = 0; i < 32; i += 8)
    dst[(long)(d0 + ty + i) * 2048 + t0 + tx] = tile[tx][ty + i];
}

// ------------- GEMM: C[M][N] = A[M][K](bf16) @ Bt[N][K](bf16)^T -------------
// m97 structure: 128x128 tile, BK=32, global_load_lds width-16 staging into
// linear k-subtiled LDS ([kg][row][8]); 2 barriers per K-step; XCD swizzle.
template <typename OutT>
__global__ __launch_bounds__(256) void k_gemm_bt(const u16* __restrict__ A,
                                                 const u16* __restrict__ Bt,
                                                 OutT* __restrict__ C,
                                                 int M, int N, int K) {
  __shared__ alignas(16) u16 As[4096];  // [kg][row][8], 8KB
  __shared__ alignas(16) u16 Bs[4096];

  // XCD-aware swizzle (nwg % 8 == 0 in all our launches)
  int nwg = gridDim.x * gridDim.y;
  int bid = blockIdx.y * gridDim.x + blockIdx.x;
  int cpx = nwg >> 3;
  int swz = (bid & 7) * cpx + (bid >> 3);
  int bx = swz % gridDim.x, by = swz / gridDim.x;

  int tid = threadIdx.x;
  int lane = tid & 63;
  int w = tid >> 6;
  int wm = (w >> 1) * 64, wn = (w & 1) * 64;
  int lr = lane & 15, lg = lane >> 4;
  long brow = (long)by * 128, bcol = (long)bx * 128;

  // staging decomposition: chunk c = w*2+i covers LDS bytes [c*1024, c*1024+1024)
  // flat u16-x8 index l = c*64 + lane -> kg = l>>7, row = l&127
  int sg[2], srow[2];
  for (int i = 0; i < 2; ++i) {
    int l = (w * 2 + i) * 64 + lane;
    sg[i] = (l >> 7) * 8;     // k offset within BK
    srow[i] = l & 127;        // tile row
  }

  f32x4 zero = {0.f, 0.f, 0.f, 0.f};
  f32x4 acc[4][4];
  for (int mi = 0; mi < 4; ++mi)
    for (int ni = 0; ni < 4; ++ni) acc[mi][ni] = zero;

  const u16* Ab = A + brow * K;
  const u16* Bb = Bt + bcol * K;

  for (int k0 = 0; k0 < K; k0 += 32) {
    __syncthreads();  // previous iter's ds_reads done before DMA overwrite
    for (int i = 0; i < 2; ++i) {
      int c = w * 2 + i;
      gl16(Ab + (long)srow[i] * K + k0 + sg[i], &As[c * 512]);
      gl16(Bb + (long)srow[i] * K + k0 + sg[i], &Bs[c * 512]);
    }
    __syncthreads();  // compiler emits s_waitcnt vmcnt(0) before barrier
    bf16x8 af[4], bfr[4];
    for (int mi = 0; mi < 4; ++mi)
      af[mi] = *(const bf16x8*)&As[(lg * 128 + wm + mi * 16 + lr) * 8];
    for (int ni = 0; ni < 4; ++ni)
      bfr[ni] = *(const bf16x8*)&Bs[(lg * 128 + wn + ni * 16 + lr) * 8];
    for (int mi = 0; mi < 4; ++mi)
      for (int ni = 0; ni < 4; ++ni)
        acc[mi][ni] = mfma16(af[mi], bfr[ni], acc[mi][ni]);
  }
  // C/D layout: col = lane&15, row = (lane>>4)*4 + reg   [measured m89/m91]
  for (int mi = 0; mi < 4; ++mi)
    for (int ni = 0; ni < 4; ++ni)
      for (int r = 0; r < 4; ++r) {
        long row = brow + wm + mi * 16 + lg * 4 + r;
        long col = bcol + wn + ni * 16 + lr;
        float v = acc[mi][ni][r];
        if constexpr (sizeof(OutT) == 2)
          C[row * N + col] = (OutT)f2bf(v);
        else
          C[row * N + col] = v;
      }
}

// ------------- flash attention v2: 4 waves x 32 q-rows, KV tile 64, LDS dbuf -------------
// QKV: [8192][6144] bf16; Vt: [64][128][2048] bf16 (d-major); Y: [8192][2048] bf16
// Grid: x = bh (64), y = 16 (qb = 15 - y, heavy tiles dispatched first)
__global__ __launch_bounds__(256, 2) void k_attn2(const u16* __restrict__ qkv,
                                                  const u16* __restrict__ vt,
                                                  u16* __restrict__ y) {
  __shared__ alignas(16) u16 Ks[2][64 * 128];   // [row t][chunk-swizzled d], 16KB each
  __shared__ alignas(16) u16 Vs[2][128 * 64];   // [row d][chunk-swizzled t], 16KB each
  __shared__ alignas(16) u16 Ps[4][32 * 64];    // per-wave P, swizzled, 4KB each

  int bh = blockIdx.x;
  int qb = 15 - (int)blockIdx.y;
  int b = bh >> 4, h = bh & 15;
  int tid = threadIdx.x;
  int lane = tid & 63;
  int w = tid >> 6;
  int lr = lane & 15, lg = lane >> 4;
  int x7 = lr & 7;
  const float scale = 0.08838834764831845f;  // 1/sqrt(128)

  const u16* kbase = qkv + (long)(b * 2048) * 6144 + 2048 + h * 128;
  const u16* vtbh = vt + (long)bh * 128 * 2048;
  int qbase = qb * 128 + w * 32;

  // Q fragments (B-operand of swapped QK^T): lane lr = q row, lg = d-subgroup
  const u16* qptr = qkv + (long)(qb * 128 + b * 2048) * 6144 + h * 128;
  bf16x8 qf[2][4];
  for (int qsub = 0; qsub < 2; ++qsub)
    for (int dc = 0; dc < 4; ++dc)
      qf[qsub][dc] = *(const bf16x8*)(qptr + (long)(w * 32 + qsub * 16 + lr) * 6144 + dc * 32 + lg * 8);

  f32x4 zero = {0.f, 0.f, 0.f, 0.f};
  f32x4 o[2][8];
  for (int qs = 0; qs < 2; ++qs)
    for (int ds = 0; ds < 8; ++ds) o[qs][ds] = zero;
  float m_run[2] = {-1e30f, -1e30f};
  float l_run[2] = {0.f, 0.f};

  int nkt = 2 * qb + 2;
  int qmaxw = qbase + 31;
  u16* Pw = &Ps[w][0];

#define STAGE(BUF, KT)                                                          \
  do {                                                                          \
    for (int i_ = 0; i_ < 4; ++i_) {                                            \
      int rl_ = w * 16 + i_ * 4;                                                \
      int row_ = rl_ + (lane >> 4);                                             \
      int ch_ = (lane & 15) ^ (row_ & 7);                                       \
      gl16(kbase + (long)((KT)*64 + row_) * 6144 + ch_ * 8, &Ks[BUF][rl_ * 128]); \
    }                                                                           \
    for (int i_ = 0; i_ < 4; ++i_) {                                            \
      int dl_ = w * 32 + i_ * 8;                                                \
      int d_ = dl_ + (lane >> 3);                                               \
      int ch_ = (lane & 7) ^ (d_ & 7);                                          \
      gl16(vtbh + (long)d_ * 2048 + (KT)*64 + ch_ * 8, &Vs[BUF][dl_ * 64]);     \
    }                                                                           \
  } while (0)

#define COMPUTE(BUF, KT)                                                        \
  do {                                                                          \
    const u16* Kb = &Ks[BUF][0];                                                \
    const u16* Vb = &Vs[BUF][0];                                                \
    f32x4 s[2][4];                                                              \
    for (int qs = 0; qs < 2; ++qs)                                              \
      for (int ks = 0; ks < 4; ++ks) s[qs][ks] = zero;                          \
    for (int ks = 0; ks < 4; ++ks) {                                            \
      int row = ks * 16 + lr;                                                   \
      for (int dc = 0; dc < 4; ++dc) {                                          \
        bf16x8 kf = *(const bf16x8*)(Kb + row * 128 + ((dc * 4 + lg) ^ x7) * 8); \
        s[0][ks] = mfma16(kf, qf[0][dc], s[0][ks]);                             \
        s[1][ks] = mfma16(kf, qf[1][dc], s[1][ks]);                             \
      }                                                                         \
    }                                                                           \
    for (int qs = 0; qs < 2; ++qs) {                                            \
      int qg = qbase + qs * 16 + lr;                                            \
      float p[16];                                                              \
      float tmax = -1e30f;                                                      \
      for (int ks = 0; ks < 4; ++ks)                                            \
        for (int r = 0; r < 4; ++r) {                                           \
          int key = (KT)*64 + ks * 16 + lg * 4 + r;                             \
          float v = (key <= qg) ? s[qs][ks][r] * scale : -1e30f;                \
          p[ks * 4 + r] = v;                                                    \
          tmax = fmaxf(tmax, v);                                                \
        }                                                                       \
      tmax = fmaxf(tmax, __shfl_xor(tmax, 16));                                 \
      tmax = fmaxf(tmax, __shfl_xor(tmax, 32));                                 \
      float m_new = fmaxf(m_run[qs], tmax);                                     \
      float alpha = __expf(m_run[qs] - m_new);                                  \
      float psum = 0.f;                                                         \
      for (int i = 0; i < 16; ++i) {                                            \
        p[i] = __expf(p[i] - m_new);                                            \
        psum += p[i];                                                           \
      }                                                                         \
      psum += __shfl_xor(psum, 16);                                             \
      psum += __shfl_xor(psum, 32);                                             \
      l_run[qs] = l_run[qs] * alpha + psum;                                     \
      m_run[qs] = m_new;                                                        \
      int prow = qs * 16 + lr;                                                  \
      for (int ks = 0; ks < 4; ++ks) {                                          \
        U16x4 pk{f2bf(p[ks * 4 + 0]), f2bf(p[ks * 4 + 1]),                      \
                 f2bf(p[ks * 4 + 2]), f2bf(p[ks * 4 + 3])};                     \
        int chunk = ks * 2 + (lg >> 1);                                         \
        *(U16x4*)&Pw[prow * 64 + ((chunk ^ x7) * 8) + (lg & 1) * 4] = pk;       \
      }                                                                         \
      float alr[4];                                                             \
      for (int r = 0; r < 4; ++r) alr[r] = __shfl(alpha, lg * 4 + r);           \
      for (int ds = 0; ds < 8; ++ds)                                            \
        for (int r = 0; r < 4; ++r) o[qs][ds][r] *= alr[r];                     \
    }                                                                           \
    asm volatile("s_waitcnt lgkmcnt(0)" ::: "memory");                          \
    for (int j = 0; j < 2; ++j) {                                               \
      int chv = ((j * 4 + lg) ^ x7) * 8;                                        \
      bf16x8 pa0 = *(const bf16x8*)&Pw[(0 * 16 + lr) * 64 + chv];               \
      bf16x8 pa1 = *(const bf16x8*)&Pw[(1 * 16 + lr) * 64 + chv];               \
      for (int ds = 0; ds < 8; ++ds) {                                          \
        bf16x8 vf = *(const bf16x8*)(Vb + (ds * 16 + lr) * 64 + chv);           \
        o[0][ds] = mfma16(pa0, vf, o[0][ds]);                                   \
        o[1][ds] = mfma16(pa1, vf, o[1][ds]);                                   \
      }                                                                         \
    }                                                                           \
  } while (0)

  int buf = 0;
  STAGE(0, 0);
  asm volatile("s_waitcnt vmcnt(0)" ::: "memory");
  __builtin_amdgcn_s_barrier();
  for (int kt = 0; kt < nkt - 1; ++kt) {
    STAGE(buf ^ 1, kt + 1);
    if (kt * 64 <= qmaxw) COMPUTE(buf, kt);
    asm volatile("s_waitcnt vmcnt(0) lgkmcnt(0)" ::: "memory");
    __builtin_amdgcn_s_barrier();
    buf ^= 1;
  }
  {
    int kt = nkt - 1;
    if (kt * 64 <= qmaxw) COMPUTE(buf, kt);
  }
#undef STAGE
#undef COMPUTE

  float linv[2][4];
  for (int qs = 0; qs < 2; ++qs)
    for (int r = 0; r < 4; ++r) linv[qs][r] = 1.0f / __shfl(l_run[qs], lg * 4 + r);
  u16* yb = y + (long)(b * 2048 + qb * 128 + w * 32) * 2048 + h * 128;
  for (int qs = 0; qs < 2; ++qs)
    for (int ds = 0; ds < 8; ++ds)
      for (int r = 0; r < 4; ++r)
        yb[(long)(qs * 16 + lg * 4 + r) * 2048 + ds * 16 + lr] = f2bf(o[qs][ds][r] * linv[qs][r]);
}

// ------------------------------- launch -------------------------------
extern "C" void kernel_launch(void* const* d_in, const int* in_sizes, int n_in,
                              void* d_out, int out_size, void* d_ws, size_t ws_size,
                              hipStream_t stream) {
  const float* x = (const float*)d_in[0];       // [4,2048,2048]
  const float* w_qkv = (const float*)d_in[1];   // [2048,6144]
  const float* w_proj = (const float*)d_in[2];  // [2048,2048]
  float* out = (float*)d_out;                   // [4,2048,2048] fp32

  char* ws = (char*)d_ws;
  if (ws_size < 201326592ull) return;
  u16* QKV = (u16*)(ws);
  u16* WqT = (u16*)(ws + 100663296);
  u16* WpT = (u16*)(ws + 125829120);
  u16* Xb  = (u16*)(ws + 134217728);
  u16* Vt  = (u16*)(ws + 167772160);

  dim3 tb32x8(32, 8);

  k_f32_to_bf16<<<2048, 256, 0, stream>>>(x, Xb, (8192L * 2048) / 4);
  k_transpose_f32_to_bf16<<<dim3(192, 64), tb32x8, 0, stream>>>(w_qkv, WqT, 2048, 6144);
  k_transpose_f32_to_bf16<<<dim3(64, 64), tb32x8, 0, stream>>>(w_proj, WpT, 2048, 2048);

  k_gemm_bt<u16><<<dim3(48, 64), 256, 0, stream>>>(Xb, WqT, QKV, 8192, 6144, 2048);

  k_transpose_v<<<dim3(4, 64, 64), tb32x8, 0, stream>>>(QKV, Vt);

  k_attn2<<<dim3(64, 16), 256, 0, stream>>>(QKV, Vt, Xb /* Y */);

  k_gemm_bt<float><<<dim3(16, 64), 256, 0, stream>>>(Xb, WpT, out, 8192, 2048, 2048);
}

// Round 4
// 546.360 us; speedup vs baseline: 1.2797x; 1.2797x over previous
//
#include <hip/hip_runtime.h>

typedef unsigned short u16;
typedef unsigned int u32;
typedef __bf16 bf16x8 __attribute__((ext_vector_type(8)));
typedef float f32x4 __attribute__((ext_vector_type(4)));

__device__ __forceinline__ u16 f2bf(float f) {
  u32 u = __builtin_bit_cast(u32, f);
  return (u16)((u + 0x7fffu + ((u >> 16) & 1u)) >> 16);  // RNE
}

__device__ __forceinline__ f32x4 mfma16(bf16x8 a, bf16x8 b, f32x4 c) {
  return __builtin_amdgcn_mfma_f32_16x16x32_bf16(a, b, c, 0, 0, 0);
}

struct alignas(8) U16x4 { u16 x, y, z, w; };

#define AS1 __attribute__((address_space(1)))
#define AS3 __attribute__((address_space(3)))
// async global->LDS, 16B per lane; lds dest = wave-uniform base + lane*16
__device__ __forceinline__ void gl16(const u16* g, u16* l) {
  __builtin_amdgcn_global_load_lds((const AS1 u32*)g, (AS3 u32*)l, 16, 0, 0);
}

// ---------------- fp32 -> bf16 convert (vectorized) ----------------
__global__ __launch_bounds__(256) void k_f32_to_bf16(const float* __restrict__ in,
                                                     u16* __restrict__ out, long n4) {
  long i = (long)blockIdx.x * blockDim.x + threadIdx.x;
  long stride = (long)gridDim.x * blockDim.x;
  for (; i < n4; i += stride) {
    float4 v = ((const float4*)in)[i];
    U16x4 o{f2bf(v.x), f2bf(v.y), f2bf(v.z), f2bf(v.w)};
    ((U16x4*)out)[i] = o;
  }
}

// ------------- transpose fp32 [rows][cols] -> bf16 [cols][rows] -------------
__global__ __launch_bounds__(256) void k_transpose_f32_to_bf16(const float* __restrict__ in,
                                                               u16* __restrict__ out,
                                                               int rows, int cols) {
  __shared__ float tile[32][33];
  int bc = blockIdx.x * 32, br = blockIdx.y * 32;
  int tx = threadIdx.x, ty = threadIdx.y;  // 32 x 8
  for (int i = 0; i < 32; i += 8)
    tile[ty + i][tx] = in[(long)(br + ty + i) * cols + bc + tx];
  __syncthreads();
  for (int i = 0; i < 32; i += 8)
    out[(long)(bc + ty + i) * rows + br + tx] = f2bf(tile[tx][ty + i]);
}

// ------------- V slice transpose: QKV[b*T+t][4096+h*128+d] -> Vt[bh][d][t] -------------
__global__ __launch_bounds__(256) void k_transpose_v(const u16* __restrict__ qkv,
                                                     u16* __restrict__ vt) {
  __shared__ u16 tile[32][33];
  int bh = blockIdx.z; int b = bh >> 4, h = bh & 15;
  int t0 = blockIdx.y * 32, d0 = blockIdx.x * 32;
  int tx = threadIdx.x, ty = threadIdx.y;  // 32 x 8
  const u16* src = qkv + (long)(b * 2048) * 6144 + 4096 + h * 128;
  for (int i = 0; i < 32; i += 8)
    tile[ty + i][tx] = src[(long)(t0 + ty + i) * 6144 + d0 + tx];
  __syncthreads();
  u16* dst = vt + (long)bh * 128 * 2048;
  for (int i = 0; i < 32; i += 8)
    dst[(long)(d0 + ty + i) * 2048 + t0 + tx] = tile[tx][ty + i];
}

// ------------- GEMM: C[M][N] = A[M][K](bf16) @ Bt[N][K](bf16)^T -------------
// m97 structure: 128x128 tile, BK=32, global_load_lds width-16 staging.
// LDS = row-major [128][32] with involutive chunk swizzle ch' = ch ^ ((row>>1)&3):
//   - staging source: 4 consecutive lanes read a permutation of one row's 64B
//     line -> fully coalesced; LDS dest linear (rule #21).
//   - fragment ds_read_b128 at row*32 + ((lg ^ ((lr>>1)&3))*8): lanes land on
//     8 distinct (parity,chunk) slots x2 -> 2-way bank conflict = free (m136).
template <typename OutT>
__global__ __launch_bounds__(256) void k_gemm_bt(const u16* __restrict__ A,
                                                 const u16* __restrict__ Bt,
                                                 OutT* __restrict__ C,
                                                 int M, int N, int K) {
  __shared__ alignas(16) u16 As[4096];  // [row][32] chunk-swizzled, 8KB
  __shared__ alignas(16) u16 Bs[4096];

  // XCD-aware swizzle (nwg % 8 == 0 in all our launches)
  int nwg = gridDim.x * gridDim.y;
  int bid = blockIdx.y * gridDim.x + blockIdx.x;
  int cpx = nwg >> 3;
  int swzb = (bid & 7) * cpx + (bid >> 3);
  int bx = swzb % gridDim.x, by = swzb / gridDim.x;

  int tid = threadIdx.x;
  int lane = tid & 63;
  int w = tid >> 6;
  int wm = (w >> 1) * 64, wn = (w & 1) * 64;
  int lr = lane & 15, lg = lane >> 4;
  long brow = (long)by * 128, bcol = (long)bx * 128;

  // staging: load i covers chunks l = i*256 + tid (16B each)
  int srow[2], sch[2];
  for (int i = 0; i < 2; ++i) {
    int l = i * 256 + tid;
    srow[i] = l >> 2;                                  // tile row
    sch[i] = ((l & 3) ^ ((srow[i] >> 1) & 3)) << 3;    // swizzled k-chunk (u16 off)
  }

  f32x4 zero = {0.f, 0.f, 0.f, 0.f};
  f32x4 acc[4][4];
  for (int mi = 0; mi < 4; ++mi)
    for (int ni = 0; ni < 4; ++ni) acc[mi][ni] = zero;

  const u16* Ab = A + brow * K;
  const u16* Bb = Bt + bcol * K;
  int rsw = (lr >> 1) & 3;  // read-side swizzle key

  for (int k0 = 0; k0 < K; k0 += 32) {
    __syncthreads();  // previous iter's ds_reads done before DMA overwrite
    for (int i = 0; i < 2; ++i) {
      int ldsbase = i * 2048 + w * 512;  // wave-uniform, lanes add lane*16B
      gl16(Ab + (long)srow[i] * K + k0 + sch[i], &As[ldsbase]);
      gl16(Bb + (long)srow[i] * K + k0 + sch[i], &Bs[ldsbase]);
    }
    __syncthreads();  // compiler emits s_waitcnt vmcnt(0) before barrier
    bf16x8 af[4], bfr[4];
    for (int mi = 0; mi < 4; ++mi)
      af[mi] = *(const bf16x8*)&As[(wm + mi * 16 + lr) * 32 + ((lg ^ rsw) << 3)];
    for (int ni = 0; ni < 4; ++ni)
      bfr[ni] = *(const bf16x8*)&Bs[(wn + ni * 16 + lr) * 32 + ((lg ^ rsw) << 3)];
    for (int mi = 0; mi < 4; ++mi)
      for (int ni = 0; ni < 4; ++ni)
        acc[mi][ni] = mfma16(af[mi], bfr[ni], acc[mi][ni]);
  }
  // C/D layout: col = lane&15, row = (lane>>4)*4 + reg   [measured m89/m91]
  for (int mi = 0; mi < 4; ++mi)
    for (int ni = 0; ni < 4; ++ni)
      for (int r = 0; r < 4; ++r) {
        long row = brow + wm + mi * 16 + lg * 4 + r;
        long col = bcol + wn + ni * 16 + lr;
        float v = acc[mi][ni][r];
        if constexpr (sizeof(OutT) == 2)
          C[row * N + col] = (OutT)f2bf(v);
        else
          C[row * N + col] = v;
      }
}

// ------------- flash attention v2: 4 waves x 32 q-rows, KV tile 64, LDS dbuf -------------
// QKV: [8192][6144] bf16; Vt: [64][128][2048] bf16 (d-major); Y: [8192][2048] bf16
// Grid: x = bh (64), y = 16 (qb = 15 - y, heavy tiles dispatched first)
__global__ __launch_bounds__(256, 2) void k_attn2(const u16* __restrict__ qkv,
                                                  const u16* __restrict__ vt,
                                                  u16* __restrict__ y) {
  __shared__ alignas(16) u16 Ks[2][64 * 128];   // [row t][chunk-swizzled d], 16KB each
  __shared__ alignas(16) u16 Vs[2][128 * 64];   // [row d][chunk-swizzled t], 16KB each
  __shared__ alignas(16) u16 Ps[4][32 * 64];    // per-wave P, swizzled, 4KB each

  int bh = blockIdx.x;
  int qb = 15 - (int)blockIdx.y;
  int b = bh >> 4, h = bh & 15;
  int tid = threadIdx.x;
  int lane = tid & 63;
  int w = tid >> 6;
  int lr = lane & 15, lg = lane >> 4;
  int x7 = lr & 7;
  const float scale = 0.08838834764831845f;  // 1/sqrt(128)

  const u16* kbase = qkv + (long)(b * 2048) * 6144 + 2048 + h * 128;
  const u16* vtbh = vt + (long)bh * 128 * 2048;
  int qbase = qb * 128 + w * 32;

  // Q fragments (B-operand of swapped QK^T): lane lr = q row, lg = d-subgroup
  const u16* qptr = qkv + (long)(qb * 128 + b * 2048) * 6144 + h * 128;
  bf16x8 qf[2][4];
  for (int qsub = 0; qsub < 2; ++qsub)
    for (int dc = 0; dc < 4; ++dc)
      qf[qsub][dc] = *(const bf16x8*)(qptr + (long)(w * 32 + qsub * 16 + lr) * 6144 + dc * 32 + lg * 8);

  f32x4 zero = {0.f, 0.f, 0.f, 0.f};
  f32x4 o[2][8];
  for (int qs = 0; qs < 2; ++qs)
    for (int ds = 0; ds < 8; ++ds) o[qs][ds] = zero;
  float m_run[2] = {-1e30f, -1e30f};
  float l_run[2] = {0.f, 0.f};

  int nkt = 2 * qb + 2;
  int qmaxw = qbase + 31;
  u16* Pw = &Ps[w][0];

#define STAGE(BUF, KT)                                                          \
  do {                                                                          \
    for (int i_ = 0; i_ < 4; ++i_) {                                            \
      int rl_ = w * 16 + i_ * 4;                                                \
      int row_ = rl_ + (lane >> 4);                                             \
      int ch_ = (lane & 15) ^ (row_ & 7);                                       \
      gl16(kbase + (long)((KT)*64 + row_) * 6144 + ch_ * 8, &Ks[BUF][rl_ * 128]); \
    }                                                                           \
    for (int i_ = 0; i_ < 4; ++i_) {                                            \
      int dl_ = w * 32 + i_ * 8;                                                \
      int d_ = dl_ + (lane >> 3);                                               \
      int ch_ = (lane & 7) ^ (d_ & 7);                                          \
      gl16(vtbh + (long)d_ * 2048 + (KT)*64 + ch_ * 8, &Vs[BUF][dl_ * 64]);     \
    }                                                                           \
  } while (0)

#define COMPUTE(BUF, KT)                                                        \
  do {                                                                          \
    const u16* Kb = &Ks[BUF][0];                                                \
    const u16* Vb = &Vs[BUF][0];                                                \
    f32x4 s[2][4];                                                              \
    for (int qs = 0; qs < 2; ++qs)                                              \
      for (int ks = 0; ks < 4; ++ks) s[qs][ks] = zero;                          \
    for (int ks = 0; ks < 4; ++ks) {                                            \
      int row = ks * 16 + lr;                                                   \
      for (int dc = 0; dc < 4; ++dc) {                                          \
        bf16x8 kf = *(const bf16x8*)(Kb + row * 128 + ((dc * 4 + lg) ^ x7) * 8); \
        s[0][ks] = mfma16(kf, qf[0][dc], s[0][ks]);                             \
        s[1][ks] = mfma16(kf, qf[1][dc], s[1][ks]);                             \
      }                                                                         \
    }                                                                           \
    for (int qs = 0; qs < 2; ++qs) {                                            \
      int qg = qbase + qs * 16 + lr;                                            \
      float p[16];                                                              \
      float tmax = -1e30f;                                                      \
      for (int ks = 0; ks < 4; ++ks)                                            \
        for (int r = 0; r < 4; ++r) {                                           \
          int key = (KT)*64 + ks * 16 + lg * 4 + r;                             \
          float v = (key <= qg) ? s[qs][ks][r] * scale : -1e30f;                \
          p[ks * 4 + r] = v;                                                    \
          tmax = fmaxf(tmax, v);                                                \
        }                                                                       \
      tmax = fmaxf(tmax, __shfl_xor(tmax, 16));                                 \
      tmax = fmaxf(tmax, __shfl_xor(tmax, 32));                                 \
      float m_new = fmaxf(m_run[qs], tmax);                                     \
      float alpha = __expf(m_run[qs] - m_new);                                  \
      float psum = 0.f;                                                         \
      for (int i = 0; i < 16; ++i) {                                            \
        p[i] = __expf(p[i] - m_new);                                            \
        psum += p[i];                                                           \
      }                                                                         \
      psum += __shfl_xor(psum, 16);                                             \
      psum += __shfl_xor(psum, 32);                                             \
      l_run[qs] = l_run[qs] * alpha + psum;                                     \
      m_run[qs] = m_new;                                                        \
      int prow = qs * 16 + lr;                                                  \
      for (int ks = 0; ks < 4; ++ks) {                                          \
        U16x4 pk{f2bf(p[ks * 4 + 0]), f2bf(p[ks * 4 + 1]),                      \
                 f2bf(p[ks * 4 + 2]), f2bf(p[ks * 4 + 3])};                     \
        int chunk = ks * 2 + (lg >> 1);                                         \
        *(U16x4*)&Pw[prow * 64 + ((chunk ^ x7) * 8) + (lg & 1) * 4] = pk;       \
      }                                                                         \
      float alr[4];                                                             \
      for (int r = 0; r < 4; ++r) alr[r] = __shfl(alpha, lg * 4 + r);           \
      for (int ds = 0; ds < 8; ++ds)                                            \
        for (int r = 0; r < 4; ++r) o[qs][ds][r] *= alr[r];                     \
    }                                                                           \
    asm volatile("s_waitcnt lgkmcnt(0)" ::: "memory");                          \
    for (int j = 0; j < 2; ++j) {                                               \
      int chv = ((j * 4 + lg) ^ x7) * 8;                                        \
      bf16x8 pa0 = *(const bf16x8*)&Pw[(0 * 16 + lr) * 64 + chv];               \
      bf16x8 pa1 = *(const bf16x8*)&Pw[(1 * 16 + lr) * 64 + chv];               \
      for (int ds = 0; ds < 8; ++ds) {                                          \
        bf16x8 vf = *(const bf16x8*)(Vb + (ds * 16 + lr) * 64 + chv);           \
        o[0][ds] = mfma16(pa0, vf, o[0][ds]);                                   \
        o[1][ds] = mfma16(pa1, vf, o[1][ds]);                                   \
      }                                                                         \
    }                                                                           \
  } while (0)

  int buf = 0;
  STAGE(0, 0);
  asm volatile("s_waitcnt vmcnt(0)" ::: "memory");
  __builtin_amdgcn_s_barrier();
  for (int kt = 0; kt < nkt - 1; ++kt) {
    STAGE(buf ^ 1, kt + 1);
    if (kt * 64 <= qmaxw) COMPUTE(buf, kt);
    asm volatile("s_waitcnt vmcnt(0) lgkmcnt(0)" ::: "memory");
    __builtin_amdgcn_s_barrier();
    buf ^= 1;
  }
  {
    int kt = nkt - 1;
    if (kt * 64 <= qmaxw) COMPUTE(buf, kt);
  }
#undef STAGE
#undef COMPUTE

  float linv[2][4];
  for (int qs = 0; qs < 2; ++qs)
    for (int r = 0; r < 4; ++r) linv[qs][r] = 1.0f / __shfl(l_run[qs], lg * 4 + r);
  u16* yb = y + (long)(b * 2048 + qb * 128 + w * 32) * 2048 + h * 128;
  for (int qs = 0; qs < 2; ++qs)
    for (int ds = 0; ds < 8; ++ds)
      for (int r = 0; r < 4; ++r)
        yb[(long)(qs * 16 + lg * 4 + r) * 2048 + ds * 16 + lr] = f2bf(o[qs][ds][r] * linv[qs][r]);
}

// ------------------------------- launch -------------------------------
extern "C" void kernel_launch(void* const* d_in, const int* in_sizes, int n_in,
                              void* d_out, int out_size, void* d_ws, size_t ws_size,
                              hipStream_t stream) {
  const float* x = (const float*)d_in[0];       // [4,2048,2048]
  const float* w_qkv = (const float*)d_in[1];   // [2048,6144]
  const float* w_proj = (const float*)d_in[2];  // [2048,2048]
  float* out = (float*)d_out;                   // [4,2048,2048] fp32

  char* ws = (char*)d_ws;
  if (ws_size < 201326592ull) return;
  u16* QKV = (u16*)(ws);
  u16* WqT = (u16*)(ws + 100663296);
  u16* WpT = (u16*)(ws + 125829120);
  u16* Xb  = (u16*)(ws + 134217728);
  u16* Vt  = (u16*)(ws + 167772160);

  dim3 tb32x8(32, 8);

  k_f32_to_bf16<<<2048, 256, 0, stream>>>(x, Xb, (8192L * 2048) / 4);
  k_transpose_f32_to_bf16<<<dim3(192, 64), tb32x8, 0, stream>>>(w_qkv, WqT, 2048, 6144);
  k_transpose_f32_to_bf16<<<dim3(64, 64), tb32x8, 0, stream>>>(w_proj, WpT, 2048, 2048);

  k_gemm_bt<u16><<<dim3(48, 64), 256, 0, stream>>>(Xb, WqT, QKV, 8192, 6144, 2048);

  k_transpose_v<<<dim3(4, 64, 64), tb32x8, 0, stream>>>(QKV, Vt);

  k_attn2<<<dim3(64, 16), 256, 0, stream>>>(QKV, Vt, Xb /* Y */);

  k_gemm_bt<float><<<dim3(16, 64), 256, 0, stream>>>(Xb, WpT, out, 8192, 2048, 2048);
}

// Round 5
// 429.952 us; speedup vs baseline: 1.6262x; 1.2707x over previous
//
#include <hip/hip_runtime.h>

typedef unsigned short u16;
typedef unsigned int u32;
typedef __bf16 bf16x8 __attribute__((ext_vector_type(8)));
typedef float f32x4 __attribute__((ext_vector_type(4)));

__device__ __forceinline__ u16 f2bf(float f) {
  u32 u = __builtin_bit_cast(u32, f);
  return (u16)((u + 0x7fffu + ((u >> 16) & 1u)) >> 16);  // RNE
}

__device__ __forceinline__ f32x4 mfma16(bf16x8 a, bf16x8 b, f32x4 c) {
  return __builtin_amdgcn_mfma_f32_16x16x32_bf16(a, b, c, 0, 0, 0);
}

struct alignas(8) U16x4 { u16 x, y, z, w; };

#define AS1 __attribute__((address_space(1)))
#define AS3 __attribute__((address_space(3)))
// async global->LDS, 16B per lane; lds dest = wave-uniform base + lane*16
__device__ __forceinline__ void gl16(const u16* g, u16* l) {
  __builtin_amdgcn_global_load_lds((const AS1 u32*)g, (AS3 u32*)l, 16, 0, 0);
}

// ---------------- fp32 -> bf16 convert (vectorized) ----------------
__global__ __launch_bounds__(256) void k_f32_to_bf16(const float* __restrict__ in,
                                                     u16* __restrict__ out, long n4) {
  long i = (long)blockIdx.x * blockDim.x + threadIdx.x;
  long stride = (long)gridDim.x * blockDim.x;
  for (; i < n4; i += stride) {
    float4 v = ((const float4*)in)[i];
    U16x4 o{f2bf(v.x), f2bf(v.y), f2bf(v.z), f2bf(v.w)};
    ((U16x4*)out)[i] = o;
  }
}

// ------------- transpose fp32 [rows][cols] -> bf16 [cols][rows] -------------
__global__ __launch_bounds__(256) void k_transpose_f32_to_bf16(const float* __restrict__ in,
                                                               u16* __restrict__ out,
                                                               int rows, int cols) {
  __shared__ float tile[32][33];
  int bc = blockIdx.x * 32, br = blockIdx.y * 32;
  int tx = threadIdx.x, ty = threadIdx.y;  // 32 x 8
  for (int i = 0; i < 32; i += 8)
    tile[ty + i][tx] = in[(long)(br + ty + i) * cols + bc + tx];
  __syncthreads();
  for (int i = 0; i < 32; i += 8)
    out[(long)(bc + ty + i) * rows + br + tx] = f2bf(tile[tx][ty + i]);
}

// ------------- V slice transpose: QKV[b*T+t][4096+h*128+d] -> Vt[bh][d][t] -------------
__global__ __launch_bounds__(256) void k_transpose_v(const u16* __restrict__ qkv,
                                                     u16* __restrict__ vt) {
  __shared__ u16 tile[32][33];
  int bh = blockIdx.z; int b = bh >> 4, h = bh & 15;
  int t0 = blockIdx.y * 32, d0 = blockIdx.x * 32;
  int tx = threadIdx.x, ty = threadIdx.y;  // 32 x 8
  const u16* src = qkv + (long)(b * 2048) * 6144 + 4096 + h * 128;
  for (int i = 0; i < 32; i += 8)
    tile[ty + i][tx] = src[(long)(t0 + ty + i) * 6144 + d0 + tx];
  __syncthreads();
  u16* dst = vt + (long)bh * 128 * 2048;
  for (int i = 0; i < 32; i += 8)
    dst[(long)(d0 + ty + i) * 2048 + t0 + tx] = tile[tx][ty + i];
}

// ------------- GEMM 256x256: C[M][N] = A[M][K](bf16) @ Bt[N][K](bf16)^T -------------
// 8 waves (2M x 4N), 128x64 per wave. K-step 32, 4-deep rotating LDS buffers
// (stage step s+3 during step s via global_load_lds w16). ONE barrier per step,
// counted s_waitcnt vmcnt(8) before it (2 steps of loads always in flight, T4).
// LDS [256][32] per buffer, chunk swizzle c' = c ^ (row&3) (T2, 0-conflict per R4).
// setprio around MFMA clusters (T5). 2D-supertile XCD swizzle (T1).
template <typename OutT>
__global__ __launch_bounds__(512, 2) void k_gemm256(const u16* __restrict__ A,
                                                    const u16* __restrict__ Bt,
                                                    OutT* __restrict__ C,
                                                    int M, int N, int K) {
  __shared__ alignas(16) u16 As[4][8192];  // 4 x 16KB
  __shared__ alignas(16) u16 Bs[4][8192];  // 4 x 16KB  (total 128KB)

  // XCD swizzle + 2D supertile: each XCD chunk walks 4 M-tiles per N-column
  // (A-panel 4MB + B-tile 1MB fits 4MB L2). Requires nwg%8==0, gridDim.y%4==0.
  int gx = gridDim.x;
  int nwg = gx * gridDim.y;
  int bid = blockIdx.y * gx + blockIdx.x;
  int swz = (bid & 7) * (nwg >> 3) + (bid >> 3);
  int rem = swz % (gx * 4);
  int bx = rem >> 2;
  int by = (swz / (gx * 4)) * 4 + (rem & 3);

  int tid = threadIdx.x;
  int lane = tid & 63;
  int w = tid >> 6;
  int wr = w >> 2, wc = w & 3;     // wave tile: rows wr*128+[0,128), cols wc*64+[0,64)
  int lr = lane & 15, lg = lane >> 4;
  long brow = (long)by * 256, bcol = (long)bx * 256;

  // staging decomposition: load i in {0,1}: chunk q = i*512+tid of 1024 (16B each)
  int rS[2], cS[2];
#pragma unroll
  for (int i = 0; i < 2; ++i) {
    int q = i * 512 + tid;
    rS[i] = q >> 2;                          // tile row (0..255)
    cS[i] = ((q & 3) ^ (rS[i] & 3)) << 3;    // swizzled source k-chunk (u16 off)
  }
  const u16* Ab = A + brow * K;
  const u16* Bb = Bt + bcol * K;

  // fragment ds_read offsets (u16 units within one 16KB buffer)
  int offA[8], offB[4];
#pragma unroll
  for (int m = 0; m < 8; ++m) {
    int row = wr * 128 + m * 16 + lr;
    offA[m] = row * 32 + ((lg ^ (row & 3)) << 3);
  }
#pragma unroll
  for (int n = 0; n < 4; ++n) {
    int row = wc * 64 + n * 16 + lr;
    offB[n] = row * 32 + ((lg ^ (row & 3)) << 3);
  }

  f32x4 zero = {0.f, 0.f, 0.f, 0.f};
  f32x4 acc[8][4];
#pragma unroll
  for (int m = 0; m < 8; ++m)
#pragma unroll
    for (int n = 0; n < 4; ++n) acc[m][n] = zero;

  int NS = K >> 5;  // K-steps (64 for K=2048)

#define STAGE256(SBUF, KT)                                                          \
  do {                                                                              \
    int kk_ = (KT) << 5;                                                            \
    gl16(Ab + (long)rS[0] * K + kk_ + cS[0], &As[SBUF][(0 * 512 + w * 64) * 8]);    \
    gl16(Ab + (long)rS[1] * K + kk_ + cS[1], &As[SBUF][(1 * 512 + w * 64) * 8]);    \
    gl16(Bb + (long)rS[0] * K + kk_ + cS[0], &Bs[SBUF][(0 * 512 + w * 64) * 8]);    \
    gl16(Bb + (long)rS[1] * K + kk_ + cS[1], &Bs[SBUF][(1 * 512 + w * 64) * 8]);    \
  } while (0)

  // prologue: 3 steps in flight; land step 0, keep 8 outstanding
  STAGE256(0, 0);
  STAGE256(1, 1);
  STAGE256(2, 2);
  asm volatile("s_waitcnt vmcnt(8)" ::: "memory");
  __builtin_amdgcn_s_barrier();

  for (int s = 0; s < NS; ++s) {
    int cb = s & 3;
    bf16x8 af[8], bfn[4];
#pragma unroll
    for (int m = 0; m < 8; ++m) af[m] = *(const bf16x8*)&As[cb][offA[m]];
#pragma unroll
    for (int n = 0; n < 4; ++n) bfn[n] = *(const bf16x8*)&Bs[cb][offB[n]];
    // stage step s+3 (clamped address, uniform count -> vmcnt stays exact)
    int t = s + 3;
    int tb = t & 3;
    if (t > NS - 1) t = NS - 1;
    STAGE256(tb, t);
    __builtin_amdgcn_s_setprio(1);
#pragma unroll
    for (int m = 0; m < 4; ++m)
#pragma unroll
      for (int n = 0; n < 4; ++n) acc[m][n] = mfma16(af[m], bfn[n], acc[m][n]);
    __builtin_amdgcn_s_setprio(0);
    __builtin_amdgcn_s_setprio(1);
#pragma unroll
    for (int m = 4; m < 8; ++m)
#pragma unroll
      for (int n = 0; n < 4; ++n) acc[m][n] = mfma16(af[m], bfn[n], acc[m][n]);
    __builtin_amdgcn_s_setprio(0);
    // land step s+1 before the barrier; steps s+2, s+3 stay in flight (never 0)
    asm volatile("s_waitcnt vmcnt(8)" ::: "memory");
    __builtin_amdgcn_s_barrier();
  }
#undef STAGE256
  asm volatile("s_waitcnt vmcnt(0)" ::: "memory");

  // C/D layout: col = lane&15, row = (lane>>4)*4 + reg   [measured m89/m91]
#pragma unroll
  for (int m = 0; m < 8; ++m)
#pragma unroll
    for (int n = 0; n < 4; ++n)
#pragma unroll
      for (int r = 0; r < 4; ++r) {
        long row = brow + wr * 128 + m * 16 + lg * 4 + r;
        long col = bcol + wc * 64 + n * 16 + lr;
        float v = acc[m][n][r];
        if constexpr (sizeof(OutT) == 2)
          C[row * N + col] = (OutT)f2bf(v);
        else
          C[row * N + col] = v;
      }
}

// ------------- flash attention v2: 4 waves x 32 q-rows, KV tile 64, LDS dbuf -------------
// QKV: [8192][6144] bf16; Vt: [64][128][2048] bf16 (d-major); Y: [8192][2048] bf16
// Grid: x = bh (64), y = 16 (qb = 15 - y, heavy tiles dispatched first)
__global__ __launch_bounds__(256, 2) void k_attn2(const u16* __restrict__ qkv,
                                                  const u16* __restrict__ vt,
                                                  u16* __restrict__ y) {
  __shared__ alignas(16) u16 Ks[2][64 * 128];   // [row t][chunk-swizzled d], 16KB each
  __shared__ alignas(16) u16 Vs[2][128 * 64];   // [row d][chunk-swizzled t], 16KB each
  __shared__ alignas(16) u16 Ps[4][32 * 64];    // per-wave P, swizzled, 4KB each

  int bh = blockIdx.x;
  int qb = 15 - (int)blockIdx.y;
  int b = bh >> 4, h = bh & 15;
  int tid = threadIdx.x;
  int lane = tid & 63;
  int w = tid >> 6;
  int lr = lane & 15, lg = lane >> 4;
  int x7 = lr & 7;
  const float scale = 0.08838834764831845f;  // 1/sqrt(128)

  const u16* kbase = qkv + (long)(b * 2048) * 6144 + 2048 + h * 128;
  const u16* vtbh = vt + (long)bh * 128 * 2048;
  int qbase = qb * 128 + w * 32;

  // Q fragments (B-operand of swapped QK^T): lane lr = q row, lg = d-subgroup
  const u16* qptr = qkv + (long)(qb * 128 + b * 2048) * 6144 + h * 128;
  bf16x8 qf[2][4];
  for (int qsub = 0; qsub < 2; ++qsub)
    for (int dc = 0; dc < 4; ++dc)
      qf[qsub][dc] = *(const bf16x8*)(qptr + (long)(w * 32 + qsub * 16 + lr) * 6144 + dc * 32 + lg * 8);

  f32x4 zero = {0.f, 0.f, 0.f, 0.f};
  f32x4 o[2][8];
  for (int qs = 0; qs < 2; ++qs)
    for (int ds = 0; ds < 8; ++ds) o[qs][ds] = zero;
  float m_run[2] = {-1e30f, -1e30f};
  float l_run[2] = {0.f, 0.f};

  int nkt = 2 * qb + 2;
  int qmaxw = qbase + 31;
  u16* Pw = &Ps[w][0];

#define STAGE(BUF, KT)                                                          \
  do {                                                                          \
    for (int i_ = 0; i_ < 4; ++i_) {                                            \
      int rl_ = w * 16 + i_ * 4;                                                \
      int row_ = rl_ + (lane >> 4);                                             \
      int ch_ = (lane & 15) ^ (row_ & 7);                                       \
      gl16(kbase + (long)((KT)*64 + row_) * 6144 + ch_ * 8, &Ks[BUF][rl_ * 128]); \
    }                                                                           \
    for (int i_ = 0; i_ < 4; ++i_) {                                            \
      int dl_ = w * 32 + i_ * 8;                                                \
      int d_ = dl_ + (lane >> 3);                                               \
      int ch_ = (lane & 7) ^ (d_ & 7);                                          \
      gl16(vtbh + (long)d_ * 2048 + (KT)*64 + ch_ * 8, &Vs[BUF][dl_ * 64]);     \
    }                                                                           \
  } while (0)

#define COMPUTE(BUF, KT)                                                        \
  do {                                                                          \
    const u16* Kb = &Ks[BUF][0];                                                \
    const u16* Vb = &Vs[BUF][0];                                                \
    f32x4 s[2][4];                                                              \
    for (int qs = 0; qs < 2; ++qs)                                              \
      for (int ks = 0; ks < 4; ++ks) s[qs][ks] = zero;                          \
    for (int ks = 0; ks < 4; ++ks) {                                            \
      int row = ks * 16 + lr;                                                   \
      for (int dc = 0; dc < 4; ++dc) {                                          \
        bf16x8 kf = *(const bf16x8*)(Kb + row * 128 + ((dc * 4 + lg) ^ x7) * 8); \
        s[0][ks] = mfma16(kf, qf[0][dc], s[0][ks]);                             \
        s[1][ks] = mfma16(kf, qf[1][dc], s[1][ks]);                             \
      }                                                                         \
    }                                                                           \
    for (int qs = 0; qs < 2; ++qs) {                                            \
      int qg = qbase + qs * 16 + lr;                                            \
      float p[16];                                                              \
      float tmax = -1e30f;                                                      \
      for (int ks = 0; ks < 4; ++ks)                                            \
        for (int r = 0; r < 4; ++r) {                                           \
          int key = (KT)*64 + ks * 16 + lg * 4 + r;                             \
          float v = (key <= qg) ? s[qs][ks][r] * scale : -1e30f;                \
          p[ks * 4 + r] = v;                                                    \
          tmax = fmaxf(tmax, v);                                                \
        }                                                                       \
      tmax = fmaxf(tmax, __shfl_xor(tmax, 16));                                 \
      tmax = fmaxf(tmax, __shfl_xor(tmax, 32));                                 \
      float m_new = fmaxf(m_run[qs], tmax);                                     \
      float alpha = __expf(m_run[qs] - m_new);                                  \
      float psum = 0.f;                                                         \
      for (int i = 0; i < 16; ++i) {                                            \
        p[i] = __expf(p[i] - m_new);                                            \
        psum += p[i];                                                           \
      }                                                                         \
      psum += __shfl_xor(psum, 16);                                             \
      psum += __shfl_xor(psum, 32);                                             \
      l_run[qs] = l_run[qs] * alpha + psum;                                     \
      m_run[qs] = m_new;                                                        \
      int prow = qs * 16 + lr;                                                  \
      for (int ks = 0; ks < 4; ++ks) {                                          \
        U16x4 pk{f2bf(p[ks * 4 + 0]), f2bf(p[ks * 4 + 1]),                      \
                 f2bf(p[ks * 4 + 2]), f2bf(p[ks * 4 + 3])};                     \
        int chunk = ks * 2 + (lg >> 1);                                         \
        *(U16x4*)&Pw[prow * 64 + ((chunk ^ x7) * 8) + (lg & 1) * 4] = pk;       \
      }                                                                         \
      float alr[4];                                                             \
      for (int r = 0; r < 4; ++r) alr[r] = __shfl(alpha, lg * 4 + r);           \
      for (int ds = 0; ds < 8; ++ds)                                            \
        for (int r = 0; r < 4; ++r) o[qs][ds][r] *= alr[r];                     \
    }                                                                           \
    asm volatile("s_waitcnt lgkmcnt(0)" ::: "memory");                          \
    for (int j = 0; j < 2; ++j) {                                               \
      int chv = ((j * 4 + lg) ^ x7) * 8;                                        \
      bf16x8 pa0 = *(const bf16x8*)&Pw[(0 * 16 + lr) * 64 + chv];               \
      bf16x8 pa1 = *(const bf16x8*)&Pw[(1 * 16 + lr) * 64 + chv];               \
      for (int ds = 0; ds < 8; ++ds) {                                          \
        bf16x8 vf = *(const bf16x8*)(Vb + (ds * 16 + lr) * 64 + chv);           \
        o[0][ds] = mfma16(pa0, vf, o[0][ds]);                                   \
        o[1][ds] = mfma16(pa1, vf, o[1][ds]);                                   \
      }                                                                         \
    }                                                                           \
  } while (0)

  int buf = 0;
  STAGE(0, 0);
  asm volatile("s_waitcnt vmcnt(0)" ::: "memory");
  __builtin_amdgcn_s_barrier();
  for (int kt = 0; kt < nkt - 1; ++kt) {
    STAGE(buf ^ 1, kt + 1);
    if (kt * 64 <= qmaxw) COMPUTE(buf, kt);
    asm volatile("s_waitcnt vmcnt(0) lgkmcnt(0)" ::: "memory");
    __builtin_amdgcn_s_barrier();
    buf ^= 1;
  }
  {
    int kt = nkt - 1;
    if (kt * 64 <= qmaxw) COMPUTE(buf, kt);
  }
#undef STAGE
#undef COMPUTE

  float linv[2][4];
  for (int qs = 0; qs < 2; ++qs)
    for (int r = 0; r < 4; ++r) linv[qs][r] = 1.0f / __shfl(l_run[qs], lg * 4 + r);
  u16* yb = y + (long)(b * 2048 + qb * 128 + w * 32) * 2048 + h * 128;
  for (int qs = 0; qs < 2; ++qs)
    for (int ds = 0; ds < 8; ++ds)
      for (int r = 0; r < 4; ++r)
        yb[(long)(qs * 16 + lg * 4 + r) * 2048 + ds * 16 + lr] = f2bf(o[qs][ds][r] * linv[qs][r]);
}

// ------------------------------- launch -------------------------------
extern "C" void kernel_launch(void* const* d_in, const int* in_sizes, int n_in,
                              void* d_out, int out_size, void* d_ws, size_t ws_size,
                              hipStream_t stream) {
  const float* x = (const float*)d_in[0];       // [4,2048,2048]
  const float* w_qkv = (const float*)d_in[1];   // [2048,6144]
  const float* w_proj = (const float*)d_in[2];  // [2048,2048]
  float* out = (float*)d_out;                   // [4,2048,2048] fp32

  char* ws = (char*)d_ws;
  if (ws_size < 201326592ull) return;
  u16* QKV = (u16*)(ws);
  u16* WqT = (u16*)(ws + 100663296);
  u16* WpT = (u16*)(ws + 125829120);
  u16* Xb  = (u16*)(ws + 134217728);
  u16* Vt  = (u16*)(ws + 167772160);

  dim3 tb32x8(32, 8);

  k_f32_to_bf16<<<2048, 256, 0, stream>>>(x, Xb, (8192L * 2048) / 4);
  k_transpose_f32_to_bf16<<<dim3(192, 64), tb32x8, 0, stream>>>(w_qkv, WqT, 2048, 6144);
  k_transpose_f32_to_bf16<<<dim3(64, 64), tb32x8, 0, stream>>>(w_proj, WpT, 2048, 2048);

  k_gemm256<u16><<<dim3(24, 32), 512, 0, stream>>>(Xb, WqT, QKV, 8192, 6144, 2048);

  k_transpose_v<<<dim3(4, 64, 64), tb32x8, 0, stream>>>(QKV, Vt);

  k_attn2<<<dim3(64, 16), 256, 0, stream>>>(QKV, Vt, Xb /* Y */);

  k_gemm256<float><<<dim3(8, 32), 512, 0, stream>>>(Xb, WpT, out, 8192, 2048, 2048);
}

// Round 6
// 416.877 us; speedup vs baseline: 1.6772x; 1.0314x over previous
//
#include <hip/hip_runtime.h>

typedef unsigned short u16;
typedef unsigned int u32;
typedef __bf16 bf16x8 __attribute__((ext_vector_type(8)));
typedef float f32x4 __attribute__((ext_vector_type(4)));

__device__ __forceinline__ u16 f2bf(float f) {
  u32 u = __builtin_bit_cast(u32, f);
  return (u16)((u + 0x7fffu + ((u >> 16) & 1u)) >> 16);  // RNE
}

__device__ __forceinline__ f32x4 mfma16(bf16x8 a, bf16x8 b, f32x4 c) {
  return __builtin_amdgcn_mfma_f32_16x16x32_bf16(a, b, c, 0, 0, 0);
}

struct alignas(8) U16x4 { u16 x, y, z, w; };

#define AS1 __attribute__((address_space(1)))
#define AS3 __attribute__((address_space(3)))
// async global->LDS, 16B per lane; lds dest = wave-uniform base + lane*16
__device__ __forceinline__ void gl16(const u16* g, u16* l) {
  __builtin_amdgcn_global_load_lds((const AS1 u32*)g, (AS3 u32*)l, 16, 0, 0);
}

// ---------------- fp32 -> bf16 convert (vectorized) ----------------
__global__ __launch_bounds__(256) void k_f32_to_bf16(const float* __restrict__ in,
                                                     u16* __restrict__ out, long n4) {
  long i = (long)blockIdx.x * blockDim.x + threadIdx.x;
  long stride = (long)gridDim.x * blockDim.x;
  for (; i < n4; i += stride) {
    float4 v = ((const float4*)in)[i];
    U16x4 o{f2bf(v.x), f2bf(v.y), f2bf(v.z), f2bf(v.w)};
    ((U16x4*)out)[i] = o;
  }
}

// ------------- transpose fp32 [rows][cols] -> bf16 [cols][rows] -------------
__global__ __launch_bounds__(256) void k_transpose_f32_to_bf16(const float* __restrict__ in,
                                                               u16* __restrict__ out,
                                                               int rows, int cols) {
  __shared__ float tile[32][33];
  int bc = blockIdx.x * 32, br = blockIdx.y * 32;
  int tx = threadIdx.x, ty = threadIdx.y;  // 32 x 8
  for (int i = 0; i < 32; i += 8)
    tile[ty + i][tx] = in[(long)(br + ty + i) * cols + bc + tx];
  __syncthreads();
  for (int i = 0; i < 32; i += 8)
    out[(long)(bc + ty + i) * rows + br + tx] = f2bf(tile[tx][ty + i]);
}

// ------------- V slice transpose: QKV[b*T+t][4096+h*128+d] -> Vt[bh][d][t] -------------
__global__ __launch_bounds__(256) void k_transpose_v(const u16* __restrict__ qkv,
                                                     u16* __restrict__ vt) {
  __shared__ u16 tile[32][33];
  int bh = blockIdx.z; int b = bh >> 4, h = bh & 15;
  int t0 = blockIdx.y * 32, d0 = blockIdx.x * 32;
  int tx = threadIdx.x, ty = threadIdx.y;  // 32 x 8
  const u16* src = qkv + (long)(b * 2048) * 6144 + 4096 + h * 128;
  for (int i = 0; i < 32; i += 8)
    tile[ty + i][tx] = src[(long)(t0 + ty + i) * 6144 + d0 + tx];
  __syncthreads();
  u16* dst = vt + (long)bh * 128 * 2048;
  for (int i = 0; i < 32; i += 8)
    dst[(long)(d0 + ty + i) * 2048 + t0 + tx] = tile[tx][ty + i];
}

// ------------- GEMM 256x256: C[M][N] = A[M][K](bf16) @ Bt[N][K](bf16)^T -------------
// 8 waves (2M x 4N), 128x64 per wave. K-step 32, 4-deep rotating LDS buffers
// (stage step s+3 during step s via global_load_lds w16). ONE barrier per step,
// counted s_waitcnt vmcnt(8) before it (2 steps of loads always in flight, T4).
// LDS [256][32] per buffer, chunk swizzle c' = c ^ ((row>>1)&3): bank-base
// 16*(lr&1) + 4*(lg^((lr>>1)&3)) -> 8 slots x 2 lanes = 2-way = free (m136,
// verified 0-conflict in R4). setprio around MFMA clusters (T5). 2D-supertile
// XCD swizzle (T1, FETCH 147MB verified R5).
template <typename OutT>
__global__ __launch_bounds__(512, 2) void k_gemm256(const u16* __restrict__ A,
                                                    const u16* __restrict__ Bt,
                                                    OutT* __restrict__ C,
                                                    int M, int N, int K) {
  __shared__ alignas(16) u16 As[4][8192];  // 4 x 16KB
  __shared__ alignas(16) u16 Bs[4][8192];  // 4 x 16KB  (total 128KB)

  // XCD swizzle + 2D supertile: each XCD chunk walks 4 M-tiles per N-column
  // (A-panel 4MB + B-tile 1MB fits 4MB L2). Requires nwg%8==0, gridDim.y%4==0.
  int gx = gridDim.x;
  int nwg = gx * gridDim.y;
  int bid = blockIdx.y * gx + blockIdx.x;
  int swz = (bid & 7) * (nwg >> 3) + (bid >> 3);
  int rem = swz % (gx * 4);
  int bx = rem >> 2;
  int by = (swz / (gx * 4)) * 4 + (rem & 3);

  int tid = threadIdx.x;
  int lane = tid & 63;
  int w = tid >> 6;
  int wr = w >> 2, wc = w & 3;     // wave tile: rows wr*128+[0,128), cols wc*64+[0,64)
  int lr = lane & 15, lg = lane >> 4;
  long brow = (long)by * 256, bcol = (long)bx * 256;

  // staging decomposition: load i in {0,1}: chunk q = i*512+tid of 1024 (16B each)
  int rS[2], cS[2];
#pragma unroll
  for (int i = 0; i < 2; ++i) {
    int q = i * 512 + tid;
    rS[i] = q >> 2;                                 // tile row (0..255)
    cS[i] = ((q & 3) ^ ((rS[i] >> 1) & 3)) << 3;    // swizzled source k-chunk (u16 off)
  }
  const u16* Ab = A + brow * K;
  const u16* Bb = Bt + bcol * K;

  // fragment ds_read offsets (u16 units within one 16KB buffer)
  int offA[8], offB[4];
#pragma unroll
  for (int m = 0; m < 8; ++m) {
    int row = wr * 128 + m * 16 + lr;
    offA[m] = row * 32 + ((lg ^ ((row >> 1) & 3)) << 3);
  }
#pragma unroll
  for (int n = 0; n < 4; ++n) {
    int row = wc * 64 + n * 16 + lr;
    offB[n] = row * 32 + ((lg ^ ((row >> 1) & 3)) << 3);
  }

  f32x4 zero = {0.f, 0.f, 0.f, 0.f};
  f32x4 acc[8][4];
#pragma unroll
  for (int m = 0; m < 8; ++m)
#pragma unroll
    for (int n = 0; n < 4; ++n) acc[m][n] = zero;

  int NS = K >> 5;  // K-steps (64 for K=2048)

#define STAGE256(SBUF, KT)                                                          \
  do {                                                                              \
    int kk_ = (KT) << 5;                                                            \
    gl16(Ab + (long)rS[0] * K + kk_ + cS[0], &As[SBUF][(0 * 512 + w * 64) * 8]);    \
    gl16(Ab + (long)rS[1] * K + kk_ + cS[1], &As[SBUF][(1 * 512 + w * 64) * 8]);    \
    gl16(Bb + (long)rS[0] * K + kk_ + cS[0], &Bs[SBUF][(0 * 512 + w * 64) * 8]);    \
    gl16(Bb + (long)rS[1] * K + kk_ + cS[1], &Bs[SBUF][(1 * 512 + w * 64) * 8]);    \
  } while (0)

  // prologue: 3 steps in flight; land step 0, keep 8 outstanding
  STAGE256(0, 0);
  STAGE256(1, 1);
  STAGE256(2, 2);
  asm volatile("s_waitcnt vmcnt(8)" ::: "memory");
  __builtin_amdgcn_s_barrier();

  for (int s = 0; s < NS; ++s) {
    int cb = s & 3;
    bf16x8 af[8], bfn[4];
#pragma unroll
    for (int m = 0; m < 8; ++m) af[m] = *(const bf16x8*)&As[cb][offA[m]];
#pragma unroll
    for (int n = 0; n < 4; ++n) bfn[n] = *(const bf16x8*)&Bs[cb][offB[n]];
    // stage step s+3 (clamped address, uniform count -> vmcnt stays exact)
    int t = s + 3;
    int tb = t & 3;
    if (t > NS - 1) t = NS - 1;
    STAGE256(tb, t);
    __builtin_amdgcn_s_setprio(1);
#pragma unroll
    for (int m = 0; m < 4; ++m)
#pragma unroll
      for (int n = 0; n < 4; ++n) acc[m][n] = mfma16(af[m], bfn[n], acc[m][n]);
    __builtin_amdgcn_s_setprio(0);
    __builtin_amdgcn_s_setprio(1);
#pragma unroll
    for (int m = 4; m < 8; ++m)
#pragma unroll
      for (int n = 0; n < 4; ++n) acc[m][n] = mfma16(af[m], bfn[n], acc[m][n]);
    __builtin_amdgcn_s_setprio(0);
    // land step s+1 before the barrier; steps s+2, s+3 stay in flight (never 0)
    asm volatile("s_waitcnt vmcnt(8)" ::: "memory");
    __builtin_amdgcn_s_barrier();
  }
#undef STAGE256
  asm volatile("s_waitcnt vmcnt(0)" ::: "memory");

  // C/D layout: col = lane&15, row = (lane>>4)*4 + reg   [measured m89/m91]
#pragma unroll
  for (int m = 0; m < 8; ++m)
#pragma unroll
    for (int n = 0; n < 4; ++n)
#pragma unroll
      for (int r = 0; r < 4; ++r) {
        long row = brow + wr * 128 + m * 16 + lg * 4 + r;
        long col = bcol + wc * 64 + n * 16 + lr;
        float v = acc[m][n][r];
        if constexpr (sizeof(OutT) == 2)
          C[row * N + col] = (OutT)f2bf(v);
        else
          C[row * N + col] = v;
      }
}

// ------------- flash attention v2: 4 waves x 32 q-rows, KV tile 64, LDS dbuf -------------
// QKV: [8192][6144] bf16; Vt: [64][128][2048] bf16 (d-major); Y: [8192][2048] bf16
// Grid: x = bh (64), y = 16 (qb = 15 - y, heavy tiles dispatched first)
__global__ __launch_bounds__(256, 2) void k_attn2(const u16* __restrict__ qkv,
                                                  const u16* __restrict__ vt,
                                                  u16* __restrict__ y) {
  __shared__ alignas(16) u16 Ks[2][64 * 128];   // [row t][chunk-swizzled d], 16KB each
  __shared__ alignas(16) u16 Vs[2][128 * 64];   // [row d][chunk-swizzled t], 16KB each
  __shared__ alignas(16) u16 Ps[4][32 * 64];    // per-wave P, swizzled, 4KB each

  int bh = blockIdx.x;
  int qb = 15 - (int)blockIdx.y;
  int b = bh >> 4, h = bh & 15;
  int tid = threadIdx.x;
  int lane = tid & 63;
  int w = tid >> 6;
  int lr = lane & 15, lg = lane >> 4;
  int x7 = lr & 7;
  const float scale = 0.08838834764831845f;  // 1/sqrt(128)

  const u16* kbase = qkv + (long)(b * 2048) * 6144 + 2048 + h * 128;
  const u16* vtbh = vt + (long)bh * 128 * 2048;
  int qbase = qb * 128 + w * 32;

  // Q fragments (B-operand of swapped QK^T): lane lr = q row, lg = d-subgroup
  const u16* qptr = qkv + (long)(qb * 128 + b * 2048) * 6144 + h * 128;
  bf16x8 qf[2][4];
  for (int qsub = 0; qsub < 2; ++qsub)
    for (int dc = 0; dc < 4; ++dc)
      qf[qsub][dc] = *(const bf16x8*)(qptr + (long)(w * 32 + qsub * 16 + lr) * 6144 + dc * 32 + lg * 8);

  f32x4 zero = {0.f, 0.f, 0.f, 0.f};
  f32x4 o[2][8];
  for (int qs = 0; qs < 2; ++qs)
    for (int ds = 0; ds < 8; ++ds) o[qs][ds] = zero;
  float m_run[2] = {-1e30f, -1e30f};
  float l_run[2] = {0.f, 0.f};

  int nkt = 2 * qb + 2;
  int qmaxw = qbase + 31;
  u16* Pw = &Ps[w][0];

#define STAGE(BUF, KT)                                                          \
  do {                                                                          \
    for (int i_ = 0; i_ < 4; ++i_) {                                            \
      int rl_ = w * 16 + i_ * 4;                                                \
      int row_ = rl_ + (lane >> 4);                                             \
      int ch_ = (lane & 15) ^ (row_ & 7);                                       \
      gl16(kbase + (long)((KT)*64 + row_) * 6144 + ch_ * 8, &Ks[BUF][rl_ * 128]); \
    }                                                                           \
    for (int i_ = 0; i_ < 4; ++i_) {                                            \
      int dl_ = w * 32 + i_ * 8;                                                \
      int d_ = dl_ + (lane >> 3);                                               \
      int ch_ = (lane & 7) ^ (d_ & 7);                                          \
      gl16(vtbh + (long)d_ * 2048 + (KT)*64 + ch_ * 8, &Vs[BUF][dl_ * 64]);     \
    }                                                                           \
  } while (0)

#define COMPUTE(BUF, KT)                                                        \
  do {                                                                          \
    const u16* Kb = &Ks[BUF][0];                                                \
    const u16* Vb = &Vs[BUF][0];                                                \
    f32x4 s[2][4];                                                              \
    for (int qs = 0; qs < 2; ++qs)                                              \
      for (int ks = 0; ks < 4; ++ks) s[qs][ks] = zero;                          \
    for (int ks = 0; ks < 4; ++ks) {                                            \
      int row = ks * 16 + lr;                                                   \
      for (int dc = 0; dc < 4; ++dc) {                                          \
        bf16x8 kf = *(const bf16x8*)(Kb + row * 128 + ((dc * 4 + lg) ^ x7) * 8); \
        s[0][ks] = mfma16(kf, qf[0][dc], s[0][ks]);                             \
        s[1][ks] = mfma16(kf, qf[1][dc], s[1][ks]);                             \
      }                                                                         \
    }                                                                           \
    for (int qs = 0; qs < 2; ++qs) {                                            \
      int qg = qbase + qs * 16 + lr;                                            \
      float p[16];                                                              \
      float tmax = -1e30f;                                                      \
      for (int ks = 0; ks < 4; ++ks)                                            \
        for (int r = 0; r < 4; ++r) {                                           \
          int key = (KT)*64 + ks * 16 + lg * 4 + r;                             \
          float v = (key <= qg) ? s[qs][ks][r] * scale : -1e30f;                \
          p[ks * 4 + r] = v;                                                    \
          tmax = fmaxf(tmax, v);                                                \
        }                                                                       \
      tmax = fmaxf(tmax, __shfl_xor(tmax, 16));                                 \
      tmax = fmaxf(tmax, __shfl_xor(tmax, 32));                                 \
      float m_new = fmaxf(m_run[qs], tmax);                                     \
      float alpha = __expf(m_run[qs] - m_new);                                  \
      float psum = 0.f;                                                         \
      for (int i = 0; i < 16; ++i) {                                            \
        p[i] = __expf(p[i] - m_new);                                            \
        psum += p[i];                                                           \
      }                                                                         \
      psum += __shfl_xor(psum, 16);                                             \
      psum += __shfl_xor(psum, 32);                                             \
      l_run[qs] = l_run[qs] * alpha + psum;                                     \
      m_run[qs] = m_new;                                                        \
      int prow = qs * 16 + lr;                                                  \
      for (int ks = 0; ks < 4; ++ks) {                                          \
        U16x4 pk{f2bf(p[ks * 4 + 0]), f2bf(p[ks * 4 + 1]),                      \
                 f2bf(p[ks * 4 + 2]), f2bf(p[ks * 4 + 3])};                     \
        int chunk = ks * 2 + (lg >> 1);                                         \
        *(U16x4*)&Pw[prow * 64 + ((chunk ^ x7) * 8) + (lg & 1) * 4] = pk;       \
      }                                                                         \
      float alr[4];                                                             \
      for (int r = 0; r < 4; ++r) alr[r] = __shfl(alpha, lg * 4 + r);           \
      for (int ds = 0; ds < 8; ++ds)                                            \
        for (int r = 0; r < 4; ++r) o[qs][ds][r] *= alr[r];                     \
    }                                                                           \
    asm volatile("s_waitcnt lgkmcnt(0)" ::: "memory");                          \
    for (int j = 0; j < 2; ++j) {                                               \
      int chv = ((j * 4 + lg) ^ x7) * 8;                                        \
      bf16x8 pa0 = *(const bf16x8*)&Pw[(0 * 16 + lr) * 64 + chv];               \
      bf16x8 pa1 = *(const bf16x8*)&Pw[(1 * 16 + lr) * 64 + chv];               \
      for (int ds = 0; ds < 8; ++ds) {                                          \
        bf16x8 vf = *(const bf16x8*)(Vb + (ds * 16 + lr) * 64 + chv);           \
        o[0][ds] = mfma16(pa0, vf, o[0][ds]);                                   \
        o[1][ds] = mfma16(pa1, vf, o[1][ds]);                                   \
      }                                                                         \
    }                                                                           \
  } while (0)

  int buf = 0;
  STAGE(0, 0);
  asm volatile("s_waitcnt vmcnt(0)" ::: "memory");
  __builtin_amdgcn_s_barrier();
  for (int kt = 0; kt < nkt - 1; ++kt) {
    STAGE(buf ^ 1, kt + 1);
    if (kt * 64 <= qmaxw) COMPUTE(buf, kt);
    asm volatile("s_waitcnt vmcnt(0) lgkmcnt(0)" ::: "memory");
    __builtin_amdgcn_s_barrier();
    buf ^= 1;
  }
  {
    int kt = nkt - 1;
    if (kt * 64 <= qmaxw) COMPUTE(buf, kt);
  }
#undef STAGE
#undef COMPUTE

  float linv[2][4];
  for (int qs = 0; qs < 2; ++qs)
    for (int r = 0; r < 4; ++r) linv[qs][r] = 1.0f / __shfl(l_run[qs], lg * 4 + r);
  u16* yb = y + (long)(b * 2048 + qb * 128 + w * 32) * 2048 + h * 128;
  for (int qs = 0; qs < 2; ++qs)
    for (int ds = 0; ds < 8; ++ds)
      for (int r = 0; r < 4; ++r)
        yb[(long)(qs * 16 + lg * 4 + r) * 2048 + ds * 16 + lr] = f2bf(o[qs][ds][r] * linv[qs][r]);
}

// ------------------------------- launch -------------------------------
extern "C" void kernel_launch(void* const* d_in, const int* in_sizes, int n_in,
                              void* d_out, int out_size, void* d_ws, size_t ws_size,
                              hipStream_t stream) {
  const float* x = (const float*)d_in[0];       // [4,2048,2048]
  const float* w_qkv = (const float*)d_in[1];   // [2048,6144]
  const float* w_proj = (const float*)d_in[2];  // [2048,2048]
  float* out = (float*)d_out;                   // [4,2048,2048] fp32

  char* ws = (char*)d_ws;
  if (ws_size < 201326592ull) return;
  u16* QKV = (u16*)(ws);
  u16* WqT = (u16*)(ws + 100663296);
  u16* WpT = (u16*)(ws + 125829120);
  u16* Xb  = (u16*)(ws + 134217728);
  u16* Vt  = (u16*)(ws + 167772160);

  dim3 tb32x8(32, 8);

  k_f32_to_bf16<<<2048, 256, 0, stream>>>(x, Xb, (8192L * 2048) / 4);
  k_transpose_f32_to_bf16<<<dim3(192, 64), tb32x8, 0, stream>>>(w_qkv, WqT, 2048, 6144);
  k_transpose_f32_to_bf16<<<dim3(64, 64), tb32x8, 0, stream>>>(w_proj, WpT, 2048, 2048);

  k_gemm256<u16><<<dim3(24, 32), 512, 0, stream>>>(Xb, WqT, QKV, 8192, 6144, 2048);

  k_transpose_v<<<dim3(4, 64, 64), tb32x8, 0, stream>>>(QKV, Vt);

  k_attn2<<<dim3(64, 16), 256, 0, stream>>>(QKV, Vt, Xb /* Y */);

  k_gemm256<float><<<dim3(8, 32), 512, 0, stream>>>(Xb, WpT, out, 8192, 2048, 2048);
}